// Round 1
// baseline (9480.759 us; speedup 1.0000x reference)
//
#include <hip/hip_runtime.h>
#include <math.h>

// Problem constants
#define Bb 64
#define Tt 1024
#define Dd 512
#define Hh 512

// ---------------------------------------------------------------------------
// Kernel 1: xw = x @ W[:D] + b   (M=B*T=65536, K=D=512, N=H=512), fp32
// Tiled 128x128, TK=16, 256 threads, 8x8 microtile per thread.
// Writes result into d_out (same shape as final output) — scan overwrites it.
// ---------------------------------------------------------------------------
#define TM 128
#define TN 128
#define TK 16
#define LDP (TN + 4)   // padded leading dim (132 floats = 528B, 16B aligned)

__global__ __launch_bounds__(256) void gemm_xw(const float* __restrict__ x,
                                               const float* __restrict__ W,
                                               const float* __restrict__ bias,
                                               float* __restrict__ out) {
    __shared__ float As[TK][LDP];   // [k][m], transposed A tile
    __shared__ float Bs[TK][LDP];   // [k][n]

    const int tid = threadIdx.x;
    const int m0 = blockIdx.x * TM;
    const int n0 = blockIdx.y * TN;
    const int tx = tid & 15;        // n-dim
    const int ty = tid >> 4;        // m-dim

    float acc[8][8];
    #pragma unroll
    for (int i = 0; i < 8; i++)
        #pragma unroll
        for (int j = 0; j < 8; j++) acc[i][j] = 0.0f;

    for (int k0 = 0; k0 < Dd; k0 += TK) {
        // Cooperative load: A tile (TM x TK) and B tile (TK x TN), 512 float4 each.
        #pragma unroll
        for (int i = 0; i < 2; i++) {
            const int idx = tid * 2 + i;            // 0..511
            // A: row r (0..127), k-subchunk c (0..3)
            const int r = idx >> 2;
            const int c = idx & 3;
            const float4 av = *(const float4*)(x + (size_t)(m0 + r) * Dd + k0 + c * 4);
            As[c * 4 + 0][r] = av.x;
            As[c * 4 + 1][r] = av.y;
            As[c * 4 + 2][r] = av.z;
            As[c * 4 + 3][r] = av.w;
            // B: k-row kk (0..15), col group cg
            const int kk = idx >> 5;
            const int cg = (idx & 31) * 4;
            const float4 bv = *(const float4*)(W + (size_t)(k0 + kk) * Hh + n0 + cg);
            *(float4*)(&Bs[kk][cg]) = bv;
        }
        __syncthreads();

        #pragma unroll
        for (int kk = 0; kk < TK; kk++) {
            float a[8], b[8];
            #pragma unroll
            for (int i = 0; i < 8; i++) a[i] = As[kk][ty * 8 + i];
            #pragma unroll
            for (int j = 0; j < 8; j++) b[j] = Bs[kk][tx * 8 + j];
            #pragma unroll
            for (int i = 0; i < 8; i++)
                #pragma unroll
                for (int j = 0; j < 8; j++) acc[i][j] += a[i] * b[j];
        }
        __syncthreads();
    }

    // Epilogue: add bias, store.
    #pragma unroll
    for (int i = 0; i < 8; i++) {
        const size_t row = (size_t)(m0 + ty * 8 + i) * Hh;
        const int n = n0 + tx * 8;
        float4 v0, v1;
        v0.x = acc[i][0] + bias[n + 0];
        v0.y = acc[i][1] + bias[n + 1];
        v0.z = acc[i][2] + bias[n + 2];
        v0.w = acc[i][3] + bias[n + 3];
        v1.x = acc[i][4] + bias[n + 4];
        v1.y = acc[i][5] + bias[n + 5];
        v1.z = acc[i][6] + bias[n + 6];
        v1.w = acc[i][7] + bias[n + 7];
        *(float4*)(out + row + n) = v0;
        *(float4*)(out + row + n + 4) = v1;
    }
}

// ---------------------------------------------------------------------------
// Kernel 2: sequential scan. One block per batch row (recurrence is
// independent per row -> no inter-block sync needed). h lives in LDS;
// Wh (W[D:], H x H) streamed from L2 each step. In-place: reads xw from
// out[b,t,:], writes h_t back to the same location.
// ---------------------------------------------------------------------------
__global__ __launch_bounds__(512) void scan_rnn(const float* __restrict__ W,
                                                float* __restrict__ out) {
    const float* __restrict__ Wh = W + (size_t)Dd * Hh;   // W[D:], H x H row-major
    const int brow = blockIdx.x;
    const int j = threadIdx.x;                            // output column, 0..511
    float* rowbase = out + (size_t)brow * Tt * Hh;

    __shared__ float hs[Hh];
    hs[j] = 0.0f;   // h0 = 0
    __syncthreads();

    for (int t = 0; t < Tt; t++) {
        float z = rowbase[(size_t)t * Hh + j];
        #pragma unroll 16
        for (int k = 0; k < Hh; k++) {
            z += hs[k] * Wh[(size_t)k * Hh + j];
        }
        const float hn = tanhf(z);
        __syncthreads();          // all reads of hs done before overwrite
        hs[j] = hn;
        rowbase[(size_t)t * Hh + j] = hn;
        __syncthreads();          // writes visible before next step's reads
    }
}

// ---------------------------------------------------------------------------
extern "C" void kernel_launch(void* const* d_in, const int* in_sizes, int n_in,
                              void* d_out, int out_size, void* d_ws, size_t ws_size,
                              hipStream_t stream) {
    const float* x = (const float*)d_in[0];    // (B, T, D)
    const float* W = (const float*)d_in[1];    // (D+H, H)
    const float* b = (const float*)d_in[2];    // (H,)
    float* out = (float*)d_out;                // (B, T, H)

    dim3 ggrid((Bb * Tt) / TM, Hh / TN);       // 512 x 4
    gemm_xw<<<ggrid, dim3(256), 0, stream>>>(x, W, b, out);
    scan_rnn<<<dim3(Bb), dim3(512), 0, stream>>>(W, out);
}

// Round 2
// 8372.646 us; speedup vs baseline: 1.1323x; 1.1323x over previous
//
#include <hip/hip_runtime.h>
#include <math.h>

// Problem constants
#define Bb 64
#define Tt 1024
#define Dd 512
#define Hh 512

// ---------------------------------------------------------------------------
// Kernel 1: xw = x @ W[:D] + b   (M=B*T=65536, K=D=512, N=H=512), fp32
// Tiled 128x128, TK=16, 256 threads, 8x8 microtile per thread.
// Writes result into d_out (same shape as final output) — scan overwrites it.
// ---------------------------------------------------------------------------
#define TM 128
#define TN 128
#define TK 16
#define LDP (TN + 4)   // padded leading dim

__global__ __launch_bounds__(256) void gemm_xw(const float* __restrict__ x,
                                               const float* __restrict__ W,
                                               const float* __restrict__ bias,
                                               float* __restrict__ out) {
    __shared__ float As[TK][LDP];   // [k][m], transposed A tile
    __shared__ float Bs[TK][LDP];   // [k][n]

    const int tid = threadIdx.x;
    const int m0 = blockIdx.x * TM;
    const int n0 = blockIdx.y * TN;
    const int tx = tid & 15;        // n-dim
    const int ty = tid >> 4;        // m-dim

    float acc[8][8];
    #pragma unroll
    for (int i = 0; i < 8; i++)
        #pragma unroll
        for (int j = 0; j < 8; j++) acc[i][j] = 0.0f;

    for (int k0 = 0; k0 < Dd; k0 += TK) {
        #pragma unroll
        for (int i = 0; i < 2; i++) {
            const int idx = tid * 2 + i;            // 0..511
            const int r = idx >> 2;
            const int c = idx & 3;
            const float4 av = *(const float4*)(x + (size_t)(m0 + r) * Dd + k0 + c * 4);
            As[c * 4 + 0][r] = av.x;
            As[c * 4 + 1][r] = av.y;
            As[c * 4 + 2][r] = av.z;
            As[c * 4 + 3][r] = av.w;
            const int kk = idx >> 5;
            const int cg = (idx & 31) * 4;
            const float4 bv = *(const float4*)(W + (size_t)(k0 + kk) * Hh + n0 + cg);
            *(float4*)(&Bs[kk][cg]) = bv;
        }
        __syncthreads();

        #pragma unroll
        for (int kk = 0; kk < TK; kk++) {
            float a[8], b[8];
            #pragma unroll
            for (int i = 0; i < 8; i++) a[i] = As[kk][ty * 8 + i];
            #pragma unroll
            for (int j = 0; j < 8; j++) b[j] = Bs[kk][tx * 8 + j];
            #pragma unroll
            for (int i = 0; i < 8; i++)
                #pragma unroll
                for (int j = 0; j < 8; j++) acc[i][j] += a[i] * b[j];
        }
        __syncthreads();
    }

    #pragma unroll
    for (int i = 0; i < 8; i++) {
        const size_t row = (size_t)(m0 + ty * 8 + i) * Hh;
        const int n = n0 + tx * 8;
        float4 v0, v1;
        v0.x = acc[i][0] + bias[n + 0];
        v0.y = acc[i][1] + bias[n + 1];
        v0.z = acc[i][2] + bias[n + 2];
        v0.w = acc[i][3] + bias[n + 3];
        v1.x = acc[i][4] + bias[n + 4];
        v1.y = acc[i][5] + bias[n + 5];
        v1.z = acc[i][6] + bias[n + 6];
        v1.w = acc[i][7] + bias[n + 7];
        *(float4*)(out + row + n) = v0;
        *(float4*)(out + row + n + 4) = v1;
    }
}

// ---------------------------------------------------------------------------
// Kernel 2: sequential scan. One block per batch row; 1024 threads (16 waves)
// for latency hiding. Thread layout: colgroup c = tid&127 (4 columns via
// float4), k-slice s = tid>>7 (8 slices of 64 k-values each).
// Per step: each thread accumulates a float4 partial over its 64 k-values
// (float4 Wh loads from L2, float4 LDS reads of h), then an LDS reduction
// over the 8 slices + tanh by the first 512 threads.
// Wh stays fp32: the recurrence amplifies per-step noise by ~4e3, so
// fp16/bf16 weights would blow the 2e-2 threshold.
// ---------------------------------------------------------------------------
__global__ __launch_bounds__(1024) void scan_rnn(const float* __restrict__ W,
                                                 float* __restrict__ out) {
    const float* __restrict__ Wh = W + (size_t)Dd * Hh;   // (H, H) row-major
    const int brow = blockIdx.x;
    const int tid = threadIdx.x;
    const int c = tid & 127;        // column group: columns 4c..4c+3
    const int s = tid >> 7;         // k-slice: k in [64s, 64s+64)
    const int kbase = s * 64;
    float* rowbase = out + (size_t)brow * Tt * Hh;

    __shared__ float hs[Hh];          // current h, fp32
    __shared__ float ps[8][Hh];       // per-slice partials, [s][j]

    if (tid < Hh) hs[tid] = 0.0f;
    __syncthreads();

    // Wh base for this thread: row kbase, columns 4c..4c+3, as float4.
    const float4* __restrict__ wbase = (const float4*)(Wh + (size_t)kbase * Hh) + c;

    for (int t = 0; t < Tt; t++) {
        // Prefetch xw for the reduction phase (first 512 threads).
        float z = 0.0f;
        if (tid < Hh) z = rowbase[(size_t)t * Hh + tid];

        float4 acc;
        acc.x = 0.0f; acc.y = 0.0f; acc.z = 0.0f; acc.w = 0.0f;
        #pragma unroll 4
        for (int kk = 0; kk < 64; kk += 4) {
            const float4 hv = *(const float4*)&hs[kbase + kk];
            const float4 w0 = wbase[(size_t)(kk + 0) * 128];
            const float4 w1 = wbase[(size_t)(kk + 1) * 128];
            const float4 w2 = wbase[(size_t)(kk + 2) * 128];
            const float4 w3 = wbase[(size_t)(kk + 3) * 128];
            acc.x += hv.x * w0.x; acc.y += hv.x * w0.y; acc.z += hv.x * w0.z; acc.w += hv.x * w0.w;
            acc.x += hv.y * w1.x; acc.y += hv.y * w1.y; acc.z += hv.y * w1.z; acc.w += hv.y * w1.w;
            acc.x += hv.z * w2.x; acc.y += hv.z * w2.y; acc.z += hv.z * w2.z; acc.w += hv.z * w2.w;
            acc.x += hv.w * w3.x; acc.y += hv.w * w3.y; acc.z += hv.w * w3.z; acc.w += hv.w * w3.w;
        }
        *(float4*)&ps[s][4 * c] = acc;
        __syncthreads();   // all partials written, all hs reads done

        if (tid < Hh) {
            #pragma unroll
            for (int q = 0; q < 8; q++) z += ps[q][tid];
            const float hn = tanhf(z);
            hs[tid] = hn;
            rowbase[(size_t)t * Hh + tid] = hn;
        }
        __syncthreads();   // hs update visible before next step's reads
    }
}

// ---------------------------------------------------------------------------
extern "C" void kernel_launch(void* const* d_in, const int* in_sizes, int n_in,
                              void* d_out, int out_size, void* d_ws, size_t ws_size,
                              hipStream_t stream) {
    const float* x = (const float*)d_in[0];    // (B, T, D)
    const float* W = (const float*)d_in[1];    // (D+H, H)
    const float* b = (const float*)d_in[2];    // (H,)
    float* out = (float*)d_out;                // (B, T, H)

    dim3 ggrid((Bb * Tt) / TM, Hh / TN);       // 512 x 4
    gemm_xw<<<ggrid, dim3(256), 0, stream>>>(x, W, b, out);
    scan_rnn<<<dim3(Bb), dim3(1024), 0, stream>>>(W, out);
}

// Round 3
// 7879.823 us; speedup vs baseline: 1.2032x; 1.0625x over previous
//
#include <hip/hip_runtime.h>
#include <math.h>

// Problem constants
#define Bb 64
#define Tt 1024
#define Dd 512
#define Hh 512

// ---------------------------------------------------------------------------
// Kernel 1: xw = x @ W[:D] + b   (M=65536, K=512, N=512), fp32.
// Unchanged from R2 (~470 us). Writes into d_out; scan overwrites in place.
// ---------------------------------------------------------------------------
#define TM 128
#define TN 128
#define TK 16
#define LDP (TN + 4)

__global__ __launch_bounds__(256) void gemm_xw(const float* __restrict__ x,
                                               const float* __restrict__ W,
                                               const float* __restrict__ bias,
                                               float* __restrict__ out) {
    __shared__ float As[TK][LDP];
    __shared__ float Bs[TK][LDP];

    const int tid = threadIdx.x;
    const int m0 = blockIdx.x * TM;
    const int n0 = blockIdx.y * TN;
    const int tx = tid & 15;
    const int ty = tid >> 4;

    float acc[8][8];
    #pragma unroll
    for (int i = 0; i < 8; i++)
        #pragma unroll
        for (int j = 0; j < 8; j++) acc[i][j] = 0.0f;

    for (int k0 = 0; k0 < Dd; k0 += TK) {
        #pragma unroll
        for (int i = 0; i < 2; i++) {
            const int idx = tid * 2 + i;
            const int r = idx >> 2;
            const int c = idx & 3;
            const float4 av = *(const float4*)(x + (size_t)(m0 + r) * Dd + k0 + c * 4);
            As[c * 4 + 0][r] = av.x;
            As[c * 4 + 1][r] = av.y;
            As[c * 4 + 2][r] = av.z;
            As[c * 4 + 3][r] = av.w;
            const int kk = idx >> 5;
            const int cg = (idx & 31) * 4;
            const float4 bv = *(const float4*)(W + (size_t)(k0 + kk) * Hh + n0 + cg);
            *(float4*)(&Bs[kk][cg]) = bv;
        }
        __syncthreads();

        #pragma unroll
        for (int kk = 0; kk < TK; kk++) {
            float a[8], b[8];
            #pragma unroll
            for (int i = 0; i < 8; i++) a[i] = As[kk][ty * 8 + i];
            #pragma unroll
            for (int j = 0; j < 8; j++) b[j] = Bs[kk][tx * 8 + j];
            #pragma unroll
            for (int i = 0; i < 8; i++)
                #pragma unroll
                for (int j = 0; j < 8; j++) acc[i][j] += a[i] * b[j];
        }
        __syncthreads();
    }

    #pragma unroll
    for (int i = 0; i < 8; i++) {
        const size_t row = (size_t)(m0 + ty * 8 + i) * Hh;
        const int n = n0 + tx * 8;
        float4 v0, v1;
        v0.x = acc[i][0] + bias[n + 0];
        v0.y = acc[i][1] + bias[n + 1];
        v0.z = acc[i][2] + bias[n + 2];
        v0.w = acc[i][3] + bias[n + 3];
        v1.x = acc[i][4] + bias[n + 4];
        v1.y = acc[i][5] + bias[n + 5];
        v1.z = acc[i][6] + bias[n + 6];
        v1.w = acc[i][7] + bias[n + 7];
        *(float4*)(out + row + n) = v0;
        *(float4*)(out + row + n + 4) = v1;
    }
}

// ---------------------------------------------------------------------------
// Kernel 2: scan with REGISTER-RESIDENT weights.
// R2 post-mortem: per-CU L2-read port (~64 B/cy) caps any design that streams
// Wh; 1 MB/step/CU = 6.8 us/step. Fix: 4 blocks per row (column split,
// 128 cols each); each block's Wh slice (512x128 = 256 KB) lives in VGPRs
// (64 floats x 1024 threads). Zero steady-state weight traffic.
//
// Per-step h exchange among the 4 blocks of a row goes through `out` itself
// (h_t IS out[r,t,:]; every t has a distinct slot -> no overwrite hazard).
// Producer: stores + __syncthreads (drains vmcnt) + release-store flag
// (agent scope: wbl2 to Infinity Cache). Consumer: relaxed spin + 
// __threadfence (buffer_inv) + plain loads. Correct regardless of XCD
// placement; block id = c*64 + r makes a row's 4 blocks share an XCD under
// round-robin (perf heuristic only).
//
// Co-residency: 16 waves @ <=128 VGPR -> exactly 1 block/CU, 256 blocks =
// 256 CUs, all resident (capacity-exact); VGPR overflow would fail launch
// loudly, not hang.
//
// Thread layout: g = tid & 31 (4-column group), s = tid >> 5 (16-k slice).
// Weights fp32 (precision: recurrence amplifies per-step noise ~3000x;
// bf16/fp16 weights would give ~0.4-1.5 absmax >> 0.02 threshold).
// ---------------------------------------------------------------------------
__global__ __launch_bounds__(1024, 4) void scan_rnn(const float* __restrict__ W,
                                                    float* __restrict__ out,
                                                    int* __restrict__ flags) {
    const float* __restrict__ Wh = W + (size_t)Dd * Hh;   // (H, H) row-major
    const int r = blockIdx.x & 63;        // batch row
    const int c = blockIdx.x >> 6;        // column group, 0..3 (cols 128c..)
    const int tid = threadIdx.x;
    const int g = tid & 31;               // 4-col group within slice
    const int s = tid >> 5;               // k-slice, 0..31 (k in [16s,16s+16))

    float* rowbase = out + (size_t)r * Tt * Hh;
    int* myflags = flags + r * 4;

    __shared__ float hs[Hh];              // full h_{t-1}
    __shared__ float ps[32][128];         // partials [s][j_local]

    // ---- load weight slice into registers: w4[kk] = Wh[16s+kk][128c+4g..+3]
    float4 w4[16];
    {
        const float4* wbase = (const float4*)(Wh + (size_t)(s * 16) * Hh) + (c * 32 + g);
        #pragma unroll
        for (int kk = 0; kk < 16; kk++) w4[kk] = wbase[(size_t)kk * 128];
    }

    if (tid < Hh) hs[tid] = 0.0f;
    __syncthreads();

    for (int t = 0; t < Tt; t++) {
        // A: prefetch xw for own columns (written by gemm_xw)
        float z = 0.0f;
        if (tid < 128) z = rowbase[(size_t)t * Hh + c * 128 + tid];

        // B: FMA phase — 64 MACs/thread from register weights + LDS h
        float4 acc; acc.x = acc.y = acc.z = acc.w = 0.0f;
        #pragma unroll
        for (int kq = 0; kq < 4; kq++) {
            const float4 hv = *(const float4*)&hs[s * 16 + kq * 4];
            const float4 a0 = w4[kq * 4 + 0];
            const float4 a1 = w4[kq * 4 + 1];
            const float4 a2 = w4[kq * 4 + 2];
            const float4 a3 = w4[kq * 4 + 3];
            acc.x += hv.x * a0.x; acc.y += hv.x * a0.y; acc.z += hv.x * a0.z; acc.w += hv.x * a0.w;
            acc.x += hv.y * a1.x; acc.y += hv.y * a1.y; acc.z += hv.y * a1.z; acc.w += hv.y * a1.w;
            acc.x += hv.z * a2.x; acc.y += hv.z * a2.y; acc.z += hv.z * a2.z; acc.w += hv.z * a2.w;
            acc.x += hv.w * a3.x; acc.y += hv.w * a3.y; acc.z += hv.w * a3.z; acc.w += hv.w * a3.w;
        }
        *(float4*)&ps[s][g * 4] = acc;
        __syncthreads();   // partials ready; all hs reads done

        // C: finalize own 128 columns
        if (tid < 128) {
            #pragma unroll
            for (int q = 0; q < 32; q++) z += ps[q][tid];
            const float hn = tanhf(z);
            rowbase[(size_t)t * Hh + c * 128 + tid] = hn;   // publish + output
            hs[c * 128 + tid] = hn;                          // own slice locally
        }
        __syncthreads();   // drains vmcnt for ALL waves before flag

        if (t < Tt - 1) {
            // D: release flag (wbl2 -> IC, then visible device-wide)
            if (tid == 0) {
                __hip_atomic_store(&myflags[c], t + 1, __ATOMIC_RELEASE,
                                   __HIP_MEMORY_SCOPE_AGENT);
            }
            // E: wait for the 3 partners, then pull their h slices
            if (tid < 3) {
                const int cp = tid + (tid >= c ? 1 : 0);
                while (__hip_atomic_load(&myflags[cp], __ATOMIC_RELAXED,
                                         __HIP_MEMORY_SCOPE_AGENT) < t + 1) {
                    __builtin_amdgcn_s_sleep(1);
                }
                __threadfence();   // acquire: invalidate L1 + local L2
            }
            __syncthreads();
            if (tid < 384) {
                const int p = tid >> 7;
                const int cp = p + (p >= c ? 1 : 0);
                const int jj = tid & 127;
                hs[cp * 128 + jj] = rowbase[(size_t)t * Hh + cp * 128 + jj];
            }
            __syncthreads();
        }
    }
}

// ---------------------------------------------------------------------------
extern "C" void kernel_launch(void* const* d_in, const int* in_sizes, int n_in,
                              void* d_out, int out_size, void* d_ws, size_t ws_size,
                              hipStream_t stream) {
    const float* x = (const float*)d_in[0];    // (B, T, D)
    const float* W = (const float*)d_in[1];    // (D+H, H)
    const float* b = (const float*)d_in[2];    // (H,)
    float* out = (float*)d_out;                // (B, T, H)
    int* flags = (int*)d_ws;                   // 256 step-counters

    hipMemsetAsync(flags, 0, 256 * sizeof(int), stream);

    dim3 ggrid((Bb * Tt) / TM, Hh / TN);       // 512 x 4
    gemm_xw<<<ggrid, dim3(256), 0, stream>>>(x, W, b, out);
    scan_rnn<<<dim3(256), dim3(1024), 0, stream>>>(W, out, flags);
}